// Round 3
// baseline (365.297 us; speedup 1.0000x reference)
//
#include <hip/hip_runtime.h>
#include <hip/hip_bf16.h>

#define EPS 1e-5f

typedef __attribute__((ext_vector_type(8))) short short8;
typedef __attribute__((ext_vector_type(4))) short short4v;
typedef __attribute__((ext_vector_type(4))) float floatx4;

__device__ inline float b2f(short s) {
    union { unsigned u; float f; } v;
    v.u = ((unsigned)(unsigned short)s) << 16;
    return v.f;
}
__device__ inline float sigmoidf_(float x) { return 1.f / (1.f + __expf(-x)); }
__device__ inline float tanhf_(float x) { return 1.f - 2.f / (__expf(2.f * x) + 1.f); }

__device__ inline void load_lds16(const void* g, void* l) {
    __builtin_amdgcn_global_load_lds(
        (const __attribute__((address_space(1))) void*)g,
        (__attribute__((address_space(3))) void*)l, 16, 0, 0);
}

// ---------------------------------------------------------------------------
// fp32 -> bf16 converts for x, h_prev, Wi, Wh (blockIdx.y selects segment)
// ---------------------------------------------------------------------------
__global__ __launch_bounds__(256)
void cvt_bf16(const float* __restrict__ s0, __hip_bfloat16* __restrict__ d0, int n0_,
              const float* __restrict__ s1, __hip_bfloat16* __restrict__ d1, int n1_,
              const float* __restrict__ s2, __hip_bfloat16* __restrict__ d2, int n2_,
              const float* __restrict__ s3, __hip_bfloat16* __restrict__ d3, int n3_) {
    const float* s; __hip_bfloat16* d; int n;
    switch (blockIdx.y) {
        case 0:  s = s0; d = d0; n = n0_; break;
        case 1:  s = s1; d = d1; n = n1_; break;
        case 2:  s = s2; d = d2; n = n2_; break;
        default: s = s3; d = d3; n = n3_; break;
    }
    const int idx = (blockIdx.x * 256 + threadIdx.x) * 4;
    if (idx < n) {
        float4 v = *(const float4*)(s + idx);
        union { short4v sv; __hip_bfloat16 h[4]; } u;
        u.h[0] = __float2bfloat16(v.x); u.h[1] = __float2bfloat16(v.y);
        u.h[2] = __float2bfloat16(v.z); u.h[3] = __float2bfloat16(v.w);
        *(short4v*)(d + idx) = u.sv;
    }
}

// ---------------------------------------------------------------------------
// GEMM: out[m][n] = bf16( sum_k A[m][k]*W[n][k] + bias[n] )
// 128x128 tile, BK=64, 4 waves (2x2), 4x4 mfma_f32_16x16x32_bf16 per wave.
// Staging: global_load_lds width=16, XOR-swizzled chunks.
// Epilogue: acc+bias -> padded LDS -> coalesced 16B stores. Additionally
// emits per-wave partial LN stats (sum, sumsq over the wave's 64 cols) to
// sumOut/sqOut[row][64] so the LN kernel can skip its stats pass.
// ---------------------------------------------------------------------------
__global__ __launch_bounds__(256, 3)
void gemm_bf16(const __hip_bfloat16* __restrict__ A, const __hip_bfloat16* __restrict__ W,
               const float* __restrict__ bias, __hip_bfloat16* __restrict__ out,
               float* __restrict__ sumOut, float* __restrict__ sqOut, int K) {
    __shared__ alignas(16) __hip_bfloat16 smem[17408];
    __hip_bfloat16* sA = smem;
    __hip_bfloat16* sB = smem + 8192;

    const int t    = threadIdx.x;
    const int lane = t & 63;
    const int wave = t >> 6;
    const int quad = lane >> 4;
    const int rl   = lane & 15;
    const int wm   = (wave >> 1) * 64;
    const int wn   = (wave & 1) * 64;
    const int m0   = blockIdx.y * 128;
    const int n0   = blockIdx.x * 128;
    const int bn   = blockIdx.x;

    floatx4 acc[4][4];
    #pragma unroll
    for (int i = 0; i < 4; ++i)
        #pragma unroll
        for (int j = 0; j < 4; ++j)
            acc[i][j] = (floatx4){0.f, 0.f, 0.f, 0.f};

    int srow[4], scol[4];
    #pragma unroll
    for (int i = 0; i < 4; ++i) {
        const int cl  = (wave * 4 + i) * 64 + lane;
        const int row = cl >> 3;
        srow[i] = row;
        scol[i] = ((cl & 7) ^ (row & 7)) * 8;
    }

    for (int k0 = 0; k0 < K; k0 += 64) {
        __syncthreads();
        #pragma unroll
        for (int i = 0; i < 4; ++i) {
            load_lds16(A + (size_t)(m0 + srow[i]) * K + k0 + scol[i], sA + (wave * 4 + i) * 512);
            load_lds16(W + (size_t)(n0 + srow[i]) * K + k0 + scol[i], sB + (wave * 4 + i) * 512);
        }
        __syncthreads();
        #pragma unroll
        for (int kk = 0; kk < 2; ++kk) {
            short8 aF[4], bF[4];
            #pragma unroll
            for (int i = 0; i < 4; ++i) {
                const int r = wm + i * 16 + rl;
                const int c = kk * 4 + quad;
                aF[i] = *(const short8*)(sA + (r * 8 + (c ^ (r & 7))) * 8);
            }
            #pragma unroll
            for (int j = 0; j < 4; ++j) {
                const int r = wn + j * 16 + rl;
                const int c = kk * 4 + quad;
                bF[j] = *(const short8*)(sB + (r * 8 + (c ^ (r & 7))) * 8);
            }
            #pragma unroll
            for (int i = 0; i < 4; ++i)
                #pragma unroll
                for (int j = 0; j < 4; ++j)
                    acc[i][j] = __builtin_amdgcn_mfma_f32_16x16x32_bf16(aF[i], bF[j], acc[i][j], 0, 0, 0);
        }
    }

    __syncthreads();
    const bool doStats = (sumOut != nullptr);
    float bvr[4];
    #pragma unroll
    for (int j = 0; j < 4; ++j) bvr[j] = bias[n0 + wn + j * 16 + rl];

    // C/D layout: col=lane&15, row=quad*4+reg. Per-(row) stat partials
    // reduced over rl (16 lanes) x j (4 tiles) = this wave's 64 columns.
    #pragma unroll
    for (int i = 0; i < 4; ++i) {
        #pragma unroll
        for (int r = 0; r < 4; ++r) {
            const int lrow = wm + i * 16 + quad * 4 + r;
            float s = 0.f, q = 0.f;
            #pragma unroll
            for (int j = 0; j < 4; ++j) {
                const float v = acc[i][j][r] + bvr[j];
                smem[lrow * 136 + wn + j * 16 + rl] = __float2bfloat16(v);
                s += v; q += v * v;
            }
            if (doStats) {
                #pragma unroll
                for (int mask = 1; mask <= 8; mask <<= 1) {
                    s += __shfl_xor(s, mask);
                    q += __shfl_xor(q, mask);
                }
                if (rl == 0) {
                    const int grow = m0 + lrow;
                    const int part = bn * 2 + (wave & 1);
                    sumOut[(size_t)grow * 64 + part] = s;
                    sqOut[(size_t)grow * 64 + part] = q;
                }
            }
        }
    }
    __syncthreads();
    #pragma unroll
    for (int p = 0; p < 8; ++p) {
        const int ch  = p * 256 + t;
        const int row = ch >> 4;
        const int c8  = (ch & 15) * 8;
        short8 v = *(const short8*)(smem + row * 136 + c8);
        *(short8*)(out + (size_t)(m0 + row) * 4096 + n0 + c8) = v;
    }
}

// ---------------------------------------------------------------------------
// Block reduction helpers
// ---------------------------------------------------------------------------
__device__ inline void red4(float& a, float& b, float& c, float& d, float* sred) {
    #pragma unroll
    for (int off = 32; off > 0; off >>= 1) {
        a += __shfl_down(a, off); b += __shfl_down(b, off);
        c += __shfl_down(c, off); d += __shfl_down(d, off);
    }
    const int w = threadIdx.x >> 6;
    if ((threadIdx.x & 63) == 0) {
        sred[w] = a; sred[w + 4] = b; sred[w + 8] = c; sred[w + 12] = d;
    }
    __syncthreads();
    a = sred[0] + sred[1] + sred[2] + sred[3];
    b = sred[4] + sred[5] + sred[6] + sred[7];
    c = sred[8] + sred[9] + sred[10] + sred[11];
    d = sred[12] + sred[13] + sred[14] + sred[15];
    __syncthreads();
}

__device__ inline void red2(float& a, float& b, float* sred) {
    #pragma unroll
    for (int off = 32; off > 0; off >>= 1) {
        a += __shfl_down(a, off); b += __shfl_down(b, off);
    }
    const int w = threadIdx.x >> 6;
    if ((threadIdx.x & 63) == 0) { sred[w] = a; sred[w + 4] = b; }
    __syncthreads();
    a = sred[0] + sred[1] + sred[2] + sred[3];
    b = sred[4] + sred[5] + sred[6] + sred[7];
    __syncthreads();
}

// ---------------------------------------------------------------------------
// Single-pass LN+gates: stats come precomputed as 64 partials/row from the
// GEMM epilogues. Butterfly over 64 lanes -> mu/rs, then gates in registers.
// ---------------------------------------------------------------------------
__global__ __launch_bounds__(256)
void ln_gates_fast(const __hip_bfloat16* __restrict__ Pi, const __hip_bfloat16* __restrict__ Ph,
                   const float* __restrict__ c_prev,
                   const float* __restrict__ sPi, const float* __restrict__ qPi,
                   const float* __restrict__ sPh, const float* __restrict__ qPh,
                   const float* __restrict__ g_in, const float* __restrict__ b_in,
                   const float* __restrict__ g_hid, const float* __restrict__ b_hid,
                   const float* __restrict__ g_cell, const float* __restrict__ b_cell,
                   float* __restrict__ h_out, float* __restrict__ c_out) {
    const int row  = blockIdx.x;
    const int t    = threadIdx.x;
    const int lane = t & 63;
    __shared__ float sred[16];

    const __hip_bfloat16* pi = Pi + (size_t)row * 4096;
    const __hip_bfloat16* ph = Ph + (size_t)row * 4096;
    const int j0 = t * 4;

    short4v piv[4], phv[4];
    #pragma unroll
    for (int g = 0; g < 4; ++g) {
        piv[g] = *(const short4v*)(pi + g * 1024 + j0);
        phv[g] = *(const short4v*)(ph + g * 1024 + j0);
    }
    floatx4 cp = *(const floatx4*)(c_prev + (size_t)row * 1024 + j0);

    // stats: every wave redundantly reduces the 64 partials (coalesced 256B)
    float a = sPi[(size_t)row * 64 + lane];
    float b = qPi[(size_t)row * 64 + lane];
    float c = sPh[(size_t)row * 64 + lane];
    float d = qPh[(size_t)row * 64 + lane];
    #pragma unroll
    for (int mask = 1; mask <= 32; mask <<= 1) {
        a += __shfl_xor(a, mask); b += __shfl_xor(b, mask);
        c += __shfl_xor(c, mask); d += __shfl_xor(d, mask);
    }
    const float mu_i = a * (1.f / 4096.f);
    const float rs_i = rsqrtf(b * (1.f / 4096.f) - mu_i * mu_i + EPS);
    const float mu_h = c * (1.f / 4096.f);
    const float rs_h = rsqrtf(d * (1.f / 4096.f) - mu_h * mu_h + EPS);

    float comb[4][4];
    #pragma unroll
    for (int g = 0; g < 4; ++g) {
        const int col = g * 1024 + j0;
        floatx4 gi  = *(const floatx4*)(g_in  + col);
        floatx4 bii = *(const floatx4*)(b_in  + col);
        floatx4 gh  = *(const floatx4*)(g_hid + col);
        floatx4 bhh = *(const floatx4*)(b_hid + col);
        #pragma unroll
        for (int e = 0; e < 4; ++e)
            comb[g][e] = (b2f(piv[g][e]) - mu_i) * rs_i * gi[e] + bii[e]
                       + (b2f(phv[g][e]) - mu_h) * rs_h * gh[e] + bhh[e];
    }

    float cn[4], ov[4];
    float sc = 0.f, scq = 0.f;
    #pragma unroll
    for (int e = 0; e < 4; ++e) {
        const float iv = sigmoidf_(comb[0][e]);
        const float fv = sigmoidf_(comb[1][e]);
        const float gv = tanhf_(comb[2][e]);
        ov[e] = sigmoidf_(comb[3][e]);
        const float cc = fv * cp[e] + iv * gv;
        cn[e] = cc; sc += cc; scq += cc * cc;
    }
    red2(sc, scq, sred);
    const float mu_c = sc * (1.f / 1024.f);
    const float rs_c = rsqrtf(scq * (1.f / 1024.f) - mu_c * mu_c + EPS);

    floatx4 gc = *(const floatx4*)(g_cell + j0);
    floatx4 bc = *(const floatx4*)(b_cell + j0);
    floatx4 hv, cv;
    #pragma unroll
    for (int e = 0; e < 4; ++e) {
        const float nc = (cn[e] - mu_c) * rs_c * gc[e] + bc[e];
        hv[e] = ov[e] * tanhf_(nc);
        cv[e] = cn[e];
    }
    *(floatx4*)(h_out + (size_t)row * 1024 + j0) = hv;
    *(floatx4*)(c_out + (size_t)row * 1024 + j0) = cv;
}

// Fallback two-pass LN+gates (used only if ws is too small for stat arrays)
__global__ __launch_bounds__(256)
void ln_gates(const __hip_bfloat16* __restrict__ Pi, const __hip_bfloat16* __restrict__ Ph,
              const float* __restrict__ c_prev,
              const float* __restrict__ g_in, const float* __restrict__ b_in,
              const float* __restrict__ g_hid, const float* __restrict__ b_hid,
              const float* __restrict__ g_cell, const float* __restrict__ b_cell,
              float* __restrict__ h_out, float* __restrict__ c_out) {
    const int row = blockIdx.x;
    const int t   = threadIdx.x;
    __shared__ float sred[16];

    const __hip_bfloat16* pi = Pi + (size_t)row * 4096;
    const __hip_bfloat16* ph = Ph + (size_t)row * 4096;

    float si = 0.f, sqi = 0.f, sh = 0.f, sqh = 0.f;
    #pragma unroll
    for (int it = 0; it < 2; ++it) {
        const int s = t + it * 256;
        short8 vi = *(const short8*)(pi + s * 8);
        short8 vh = *(const short8*)(ph + s * 8);
        #pragma unroll
        for (int e = 0; e < 8; ++e) {
            float f = b2f(vi[e]); si += f; sqi += f * f;
            float g = b2f(vh[e]); sh += g; sqh += g * g;
        }
    }
    red4(si, sqi, sh, sqh, sred);
    const float mu_i = si * (1.f / 4096.f);
    const float rs_i = rsqrtf(sqi * (1.f / 4096.f) - mu_i * mu_i + EPS);
    const float mu_h = sh * (1.f / 4096.f);
    const float rs_h = rsqrtf(sqh * (1.f / 4096.f) - mu_h * mu_h + EPS);

    const int j0 = t * 4;
    float comb[4][4];
    #pragma unroll
    for (int g = 0; g < 4; ++g) {
        const int col = g * 1024 + j0;
        short4v vi = *(const short4v*)(pi + col);
        short4v vh = *(const short4v*)(ph + col);
        floatx4 gi  = *(const floatx4*)(g_in  + col);
        floatx4 bii = *(const floatx4*)(b_in  + col);
        floatx4 gh  = *(const floatx4*)(g_hid + col);
        floatx4 bhh = *(const floatx4*)(b_hid + col);
        #pragma unroll
        for (int e = 0; e < 4; ++e)
            comb[g][e] = (b2f(vi[e]) - mu_i) * rs_i * gi[e] + bii[e]
                       + (b2f(vh[e]) - mu_h) * rs_h * gh[e] + bhh[e];
    }

    floatx4 cp = *(const floatx4*)(c_prev + (size_t)row * 1024 + j0);
    float cn[4], ov[4];
    float sc = 0.f, scq = 0.f;
    #pragma unroll
    for (int e = 0; e < 4; ++e) {
        const float iv = sigmoidf_(comb[0][e]);
        const float fv = sigmoidf_(comb[1][e]);
        const float gv = tanhf_(comb[2][e]);
        ov[e] = sigmoidf_(comb[3][e]);
        const float c = fv * cp[e] + iv * gv;
        cn[e] = c; sc += c; scq += c * c;
    }
    red2(sc, scq, sred);
    const float mu_c = sc * (1.f / 1024.f);
    const float rs_c = rsqrtf(scq * (1.f / 1024.f) - mu_c * mu_c + EPS);

    floatx4 gc = *(const floatx4*)(g_cell + j0);
    floatx4 bc = *(const floatx4*)(b_cell + j0);
    floatx4 hv, cv;
    #pragma unroll
    for (int e = 0; e < 4; ++e) {
        const float nc = (cn[e] - mu_c) * rs_c * gc[e] + bc[e];
        hv[e] = ov[e] * tanhf_(nc);
        cv[e] = cn[e];
    }
    *(floatx4*)(h_out + (size_t)row * 1024 + j0) = hv;
    *(floatx4*)(c_out + (size_t)row * 1024 + j0) = cv;
}

// ---------------------------------------------------------------------------
extern "C" void kernel_launch(void* const* d_in, const int* in_sizes, int n_in,
                              void* d_out, int out_size, void* d_ws, size_t ws_size,
                              hipStream_t stream) {
    const float* x      = (const float*)d_in[0];
    const float* h_prev = (const float*)d_in[1];
    const float* c_prev = (const float*)d_in[2];
    const float* Wi     = (const float*)d_in[3];
    const float* bi     = (const float*)d_in[4];
    const float* Wh     = (const float*)d_in[5];
    const float* bh     = (const float*)d_in[6];
    const float* g_in   = (const float*)d_in[7];
    const float* b_in   = (const float*)d_in[8];
    const float* g_hid  = (const float*)d_in[9];
    const float* b_hid  = (const float*)d_in[10];
    const float* g_cell = (const float*)d_in[11];
    const float* b_cell = (const float*)d_in[12];

    __hip_bfloat16* Pi = (__hip_bfloat16*)d_ws;
    __hip_bfloat16* Ph = Pi + (size_t)8192 * 4096;

    const size_t base    = (size_t)2 * 8192 * 4096 * sizeof(__hip_bfloat16); // 128 MiB
    const size_t statN   = (size_t)8192 * 64;                                // per array
    const size_t need    = base + 4 * statN * sizeof(float);                 // 136 MiB
    const bool   fast    = (ws_size >= need);

    float* sPi = (float*)((char*)d_ws + base);
    float* qPi = sPi + statN;
    float* sPh = qPi + statN;
    float* qPh = sPh + statN;

    // d_out doubles as scratch for bf16-converted inputs; fully overwritten
    // by the LN kernel at the end of every call.
    const int NX = 8192 * 512, NH = 8192 * 1024, NWI = 4096 * 512, NWH = 4096 * 1024;
    __hip_bfloat16* xb  = (__hip_bfloat16*)d_out;
    __hip_bfloat16* hb  = xb + NX;
    __hip_bfloat16* Wib = hb + NH;
    __hip_bfloat16* Whb = Wib + NWI;

    float* h_out = (float*)d_out;
    float* c_out = h_out + (size_t)8192 * 1024;

    hipLaunchKernelGGL(cvt_bf16, dim3(8192, 4), dim3(256), 0, stream,
                       x, xb, NX, h_prev, hb, NH, Wi, Wib, NWI, Wh, Whb, NWH);

    dim3 grid(32, 64), blk(256);
    hipLaunchKernelGGL(gemm_bf16, grid, blk, 0, stream, xb, Wib, bi, Pi,
                       fast ? sPi : nullptr, fast ? qPi : nullptr, 512);
    hipLaunchKernelGGL(gemm_bf16, grid, blk, 0, stream, hb, Whb, bh, Ph,
                       fast ? sPh : nullptr, fast ? qPh : nullptr, 1024);
    if (fast) {
        hipLaunchKernelGGL(ln_gates_fast, dim3(8192), blk, 0, stream, Pi, Ph, c_prev,
                           sPi, qPi, sPh, qPh,
                           g_in, b_in, g_hid, b_hid, g_cell, b_cell, h_out, c_out);
    } else {
        hipLaunchKernelGGL(ln_gates, dim3(8192), blk, 0, stream, Pi, Ph, c_prev,
                           g_in, b_in, g_hid, b_hid, g_cell, b_cell, h_out, c_out);
    }
}

// Round 4
// 320.326 us; speedup vs baseline: 1.1404x; 1.1404x over previous
//
#include <hip/hip_runtime.h>
#include <hip/hip_bf16.h>

#define EPS 1e-5f

typedef __attribute__((ext_vector_type(8))) short short8;
typedef __attribute__((ext_vector_type(4))) short short4v;
typedef __attribute__((ext_vector_type(4))) float floatx4;

__device__ inline float b2f(short s) {
    union { unsigned u; float f; } v;
    v.u = ((unsigned)(unsigned short)s) << 16;
    return v.f;
}
__device__ inline float sigmoidf_(float x) { return 1.f / (1.f + __expf(-x)); }
__device__ inline float tanhf_(float x) { return 1.f - 2.f / (__expf(2.f * x) + 1.f); }

__device__ inline void load_lds16(const void* g, void* l) {
    __builtin_amdgcn_global_load_lds(
        (const __attribute__((address_space(1))) void*)g,
        (__attribute__((address_space(3))) void*)l, 16, 0, 0);
}

// ---------------------------------------------------------------------------
// fp32 -> bf16 converts for x, h_prev, Wi, Wh (blockIdx.y selects segment)
// ---------------------------------------------------------------------------
__global__ __launch_bounds__(256)
void cvt_bf16(const float* __restrict__ s0, __hip_bfloat16* __restrict__ d0, int n0_,
              const float* __restrict__ s1, __hip_bfloat16* __restrict__ d1, int n1_,
              const float* __restrict__ s2, __hip_bfloat16* __restrict__ d2, int n2_,
              const float* __restrict__ s3, __hip_bfloat16* __restrict__ d3, int n3_) {
    const float* s; __hip_bfloat16* d; int n;
    switch (blockIdx.y) {
        case 0:  s = s0; d = d0; n = n0_; break;
        case 1:  s = s1; d = d1; n = n1_; break;
        case 2:  s = s2; d = d2; n = n2_; break;
        default: s = s3; d = d3; n = n3_; break;
    }
    const int idx = (blockIdx.x * 256 + threadIdx.x) * 4;
    if (idx < n) {
        float4 v = *(const float4*)(s + idx);
        union { short4v sv; __hip_bfloat16 h[4]; } u;
        u.h[0] = __float2bfloat16(v.x); u.h[1] = __float2bfloat16(v.y);
        u.h[2] = __float2bfloat16(v.z); u.h[3] = __float2bfloat16(v.w);
        *(short4v*)(d + idx) = u.sv;
    }
}

// ---------------------------------------------------------------------------
// Dual GEMM in one dispatch: blockIdx.z selects {A,W,bias,out,K}.
// out[m][n] = bf16( sum_k A[m][k]*W[n][k] + bias[n] )
// 128x128 tile, BK=64, 4 waves (2x2), 4x4 mfma_f32_16x16x32_bf16 per wave.
// Staging: global_load_lds width=16, XOR-swizzled chunks (no padding allowed
// with load-lds; swizzle keeps ds_read_b128 at <=2-way bank alias = free).
// Epilogue: acc+bias -> padded LDS (stride 136) -> coalesced 16B stores.
// ---------------------------------------------------------------------------
__global__ __launch_bounds__(256, 3)
void gemm_dual(const __hip_bfloat16* __restrict__ A0, const __hip_bfloat16* __restrict__ W0,
               const float* __restrict__ bias0, __hip_bfloat16* __restrict__ out0, int K0,
               const __hip_bfloat16* __restrict__ A1, const __hip_bfloat16* __restrict__ W1,
               const float* __restrict__ bias1, __hip_bfloat16* __restrict__ out1, int K1) {
    __shared__ alignas(16) __hip_bfloat16 smem[17408];
    __hip_bfloat16* sA = smem;
    __hip_bfloat16* sB = smem + 8192;

    const __hip_bfloat16* A;  const __hip_bfloat16* W;
    const float* bias;        __hip_bfloat16* out;  int K;
    if (blockIdx.z == 0) { A = A0; W = W0; bias = bias0; out = out0; K = K0; }
    else                 { A = A1; W = W1; bias = bias1; out = out1; K = K1; }

    const int t    = threadIdx.x;
    const int lane = t & 63;
    const int wave = t >> 6;
    const int quad = lane >> 4;
    const int rl   = lane & 15;
    const int wm   = (wave >> 1) * 64;
    const int wn   = (wave & 1) * 64;
    const int m0   = blockIdx.y * 128;
    const int n0   = blockIdx.x * 128;

    floatx4 acc[4][4];
    #pragma unroll
    for (int i = 0; i < 4; ++i)
        #pragma unroll
        for (int j = 0; j < 4; ++j)
            acc[i][j] = (floatx4){0.f, 0.f, 0.f, 0.f};

    // staging mapping: linear chunk cl = (wave*4+i)*64 + lane
    // row = cl>>3, slot = cl&7, global k-chunk = slot ^ (row&7)
    int srow[4], scol[4];
    #pragma unroll
    for (int i = 0; i < 4; ++i) {
        const int cl  = (wave * 4 + i) * 64 + lane;
        const int row = cl >> 3;
        srow[i] = row;
        scol[i] = ((cl & 7) ^ (row & 7)) * 8;
    }

    for (int k0 = 0; k0 < K; k0 += 64) {
        __syncthreads();
        #pragma unroll
        for (int i = 0; i < 4; ++i) {
            load_lds16(A + (size_t)(m0 + srow[i]) * K + k0 + scol[i], sA + (wave * 4 + i) * 512);
            load_lds16(W + (size_t)(n0 + srow[i]) * K + k0 + scol[i], sB + (wave * 4 + i) * 512);
        }
        __syncthreads();
        #pragma unroll
        for (int kk = 0; kk < 2; ++kk) {
            short8 aF[4], bF[4];
            #pragma unroll
            for (int i = 0; i < 4; ++i) {
                const int r = wm + i * 16 + rl;
                const int c = kk * 4 + quad;
                aF[i] = *(const short8*)(sA + (r * 8 + (c ^ (r & 7))) * 8);
            }
            #pragma unroll
            for (int j = 0; j < 4; ++j) {
                const int r = wn + j * 16 + rl;
                const int c = kk * 4 + quad;
                bF[j] = *(const short8*)(sB + (r * 8 + (c ^ (r & 7))) * 8);
            }
            #pragma unroll
            for (int i = 0; i < 4; ++i)
                #pragma unroll
                for (int j = 0; j < 4; ++j)
                    acc[i][j] = __builtin_amdgcn_mfma_f32_16x16x32_bf16(aF[i], bF[j], acc[i][j], 0, 0, 0);
        }
    }

    __syncthreads();
    // epilogue: bias + cvt into padded LDS. C/D layout: col=lane&15, row=quad*4+reg.
    #pragma unroll
    for (int j = 0; j < 4; ++j) {
        const int col = wn + j * 16 + rl;
        const float bv = bias[n0 + col];
        #pragma unroll
        for (int i = 0; i < 4; ++i) {
            const int rbase = wm + i * 16 + quad * 4;
            #pragma unroll
            for (int r = 0; r < 4; ++r)
                smem[(rbase + r) * 136 + col] = __float2bfloat16(acc[i][j][r] + bv);
        }
    }
    __syncthreads();
    #pragma unroll
    for (int p = 0; p < 8; ++p) {
        const int ch  = p * 256 + t;
        const int row = ch >> 4;
        const int c8  = (ch & 15) * 8;
        short8 v = *(const short8*)(smem + row * 136 + c8);
        *(short8*)(out + (size_t)(m0 + row) * 4096 + n0 + c8) = v;
    }
}

// ---------------------------------------------------------------------------
// Single-pass LN+gates: each thread loads exactly the 16 Pi + 16 Ph elements
// it will use for the gates (registers), computes stat partials from those
// same registers, block-reduces, then applies LN+gates with no reload.
// ---------------------------------------------------------------------------
__device__ inline void red4(float& a, float& b, float& c, float& d, float* sred) {
    #pragma unroll
    for (int off = 32; off > 0; off >>= 1) {
        a += __shfl_down(a, off); b += __shfl_down(b, off);
        c += __shfl_down(c, off); d += __shfl_down(d, off);
    }
    const int w = threadIdx.x >> 6;
    if ((threadIdx.x & 63) == 0) {
        sred[w] = a; sred[w + 4] = b; sred[w + 8] = c; sred[w + 12] = d;
    }
    __syncthreads();
    a = sred[0] + sred[1] + sred[2] + sred[3];
    b = sred[4] + sred[5] + sred[6] + sred[7];
    c = sred[8] + sred[9] + sred[10] + sred[11];
    d = sred[12] + sred[13] + sred[14] + sred[15];
    __syncthreads();
}

__device__ inline void red2(float& a, float& b, float* sred) {
    #pragma unroll
    for (int off = 32; off > 0; off >>= 1) {
        a += __shfl_down(a, off); b += __shfl_down(b, off);
    }
    const int w = threadIdx.x >> 6;
    if ((threadIdx.x & 63) == 0) { sred[w] = a; sred[w + 4] = b; }
    __syncthreads();
    a = sred[0] + sred[1] + sred[2] + sred[3];
    b = sred[4] + sred[5] + sred[6] + sred[7];
    __syncthreads();
}

__global__ __launch_bounds__(256)
void ln_gates(const __hip_bfloat16* __restrict__ Pi, const __hip_bfloat16* __restrict__ Ph,
              const float* __restrict__ c_prev,
              const float* __restrict__ g_in, const float* __restrict__ b_in,
              const float* __restrict__ g_hid, const float* __restrict__ b_hid,
              const float* __restrict__ g_cell, const float* __restrict__ b_cell,
              float* __restrict__ h_out, float* __restrict__ c_out) {
    const int row = blockIdx.x;
    const int t   = threadIdx.x;
    __shared__ float sred[16];

    const __hip_bfloat16* pi = Pi + (size_t)row * 4096;
    const __hip_bfloat16* ph = Ph + (size_t)row * 4096;
    const int j0 = t * 4;

    // single load of everything this thread will use
    float fpi[4][4], fph[4][4];
    float si = 0.f, sqi = 0.f, sh = 0.f, sqh = 0.f;
    #pragma unroll
    for (int g = 0; g < 4; ++g) {
        const int col = g * 1024 + j0;
        short4v vi = *(const short4v*)(pi + col);
        short4v vh = *(const short4v*)(ph + col);
        #pragma unroll
        for (int e = 0; e < 4; ++e) {
            const float f = b2f(vi[e]); fpi[g][e] = f; si += f; sqi += f * f;
            const float g2 = b2f(vh[e]); fph[g][e] = g2; sh += g2; sqh += g2 * g2;
        }
    }
    floatx4 cp = *(const floatx4*)(c_prev + (size_t)row * 1024 + j0);

    red4(si, sqi, sh, sqh, sred);
    const float mu_i = si * (1.f / 4096.f);
    const float rs_i = rsqrtf(sqi * (1.f / 4096.f) - mu_i * mu_i + EPS);
    const float mu_h = sh * (1.f / 4096.f);
    const float rs_h = rsqrtf(sqh * (1.f / 4096.f) - mu_h * mu_h + EPS);

    float comb[4][4];
    #pragma unroll
    for (int g = 0; g < 4; ++g) {
        const int col = g * 1024 + j0;
        floatx4 gi  = *(const floatx4*)(g_in  + col);
        floatx4 bii = *(const floatx4*)(b_in  + col);
        floatx4 gh  = *(const floatx4*)(g_hid + col);
        floatx4 bhh = *(const floatx4*)(b_hid + col);
        #pragma unroll
        for (int e = 0; e < 4; ++e)
            comb[g][e] = (fpi[g][e] - mu_i) * rs_i * gi[e] + bii[e]
                       + (fph[g][e] - mu_h) * rs_h * gh[e] + bhh[e];
    }

    float cn[4], ov[4];
    float sc = 0.f, scq = 0.f;
    #pragma unroll
    for (int e = 0; e < 4; ++e) {
        const float iv = sigmoidf_(comb[0][e]);
        const float fv = sigmoidf_(comb[1][e]);
        const float gv = tanhf_(comb[2][e]);
        ov[e] = sigmoidf_(comb[3][e]);
        const float c = fv * cp[e] + iv * gv;
        cn[e] = c; sc += c; scq += c * c;
    }
    red2(sc, scq, sred);
    const float mu_c = sc * (1.f / 1024.f);
    const float rs_c = rsqrtf(scq * (1.f / 1024.f) - mu_c * mu_c + EPS);

    floatx4 gc = *(const floatx4*)(g_cell + j0);
    floatx4 bc = *(const floatx4*)(b_cell + j0);
    floatx4 hv, cv;
    #pragma unroll
    for (int e = 0; e < 4; ++e) {
        const float nc = (cn[e] - mu_c) * rs_c * gc[e] + bc[e];
        hv[e] = ov[e] * tanhf_(nc);
        cv[e] = cn[e];
    }
    *(floatx4*)(h_out + (size_t)row * 1024 + j0) = hv;
    *(floatx4*)(c_out + (size_t)row * 1024 + j0) = cv;
}

// ---------------------------------------------------------------------------
extern "C" void kernel_launch(void* const* d_in, const int* in_sizes, int n_in,
                              void* d_out, int out_size, void* d_ws, size_t ws_size,
                              hipStream_t stream) {
    const float* x      = (const float*)d_in[0];
    const float* h_prev = (const float*)d_in[1];
    const float* c_prev = (const float*)d_in[2];
    const float* Wi     = (const float*)d_in[3];
    const float* bi     = (const float*)d_in[4];
    const float* Wh     = (const float*)d_in[5];
    const float* bh     = (const float*)d_in[6];
    const float* g_in   = (const float*)d_in[7];
    const float* b_in   = (const float*)d_in[8];
    const float* g_hid  = (const float*)d_in[9];
    const float* b_hid  = (const float*)d_in[10];
    const float* g_cell = (const float*)d_in[11];
    const float* b_cell = (const float*)d_in[12];

    __hip_bfloat16* Pi = (__hip_bfloat16*)d_ws;               // 64 MiB
    __hip_bfloat16* Ph = Pi + (size_t)8192 * 4096;            // 64 MiB

    // d_out doubles as scratch for bf16-converted inputs; ln_gates fully
    // overwrites all 64 MiB of d_out at the end of every call.
    const int NX = 8192 * 512, NH = 8192 * 1024, NWI = 4096 * 512, NWH = 4096 * 1024;
    __hip_bfloat16* xb  = (__hip_bfloat16*)d_out;
    __hip_bfloat16* hb  = xb + NX;
    __hip_bfloat16* Wib = hb + NH;
    __hip_bfloat16* Whb = Wib + NWI;

    float* h_out = (float*)d_out;
    float* c_out = h_out + (size_t)8192 * 1024;

    hipLaunchKernelGGL(cvt_bf16, dim3(8192, 4), dim3(256), 0, stream,
                       x, xb, NX, h_prev, hb, NH, Wi, Wib, NWI, Wh, Whb, NWH);

    // both GEMMs in one dispatch (independent inputs/outputs; z selects)
    hipLaunchKernelGGL(gemm_dual, dim3(32, 64, 2), dim3(256), 0, stream,
                       xb, Wib, bi, Pi, 512,
                       hb, Whb, bh, Ph, 1024);

    hipLaunchKernelGGL(ln_gates, dim3(8192), dim3(256), 0, stream, Pi, Ph, c_prev,
                       g_in, b_in, g_hid, b_hid, g_cell, b_cell, h_out, c_out);
}

// Round 5
// 317.445 us; speedup vs baseline: 1.1507x; 1.0091x over previous
//
#include <hip/hip_runtime.h>
#include <hip/hip_bf16.h>

#define EPS 1e-5f

typedef __attribute__((ext_vector_type(8))) short short8;
typedef __attribute__((ext_vector_type(4))) short short4v;
typedef __attribute__((ext_vector_type(4))) float floatx4;

__device__ inline float b2f(short s) {
    union { unsigned u; float f; } v;
    v.u = ((unsigned)(unsigned short)s) << 16;
    return v.f;
}
__device__ inline float sigmoidf_(float x) { return 1.f / (1.f + __expf(-x)); }
__device__ inline float tanhf_(float x) { return 1.f - 2.f / (__expf(2.f * x) + 1.f); }

__device__ inline void load_lds16(const void* g, void* l) {
    __builtin_amdgcn_global_load_lds(
        (const __attribute__((address_space(1))) void*)g,
        (__attribute__((address_space(3))) void*)l, 16, 0, 0);
}

// ---------------------------------------------------------------------------
// fp32 -> bf16 converts for x, h_prev, Wi, Wh (blockIdx.y selects segment).
// 8 floats/thread: two float4 loads + one 16B short8 store.
// ---------------------------------------------------------------------------
__global__ __launch_bounds__(256)
void cvt_bf16(const float* __restrict__ s0, __hip_bfloat16* __restrict__ d0, int n0_,
              const float* __restrict__ s1, __hip_bfloat16* __restrict__ d1, int n1_,
              const float* __restrict__ s2, __hip_bfloat16* __restrict__ d2, int n2_,
              const float* __restrict__ s3, __hip_bfloat16* __restrict__ d3, int n3_) {
    const float* s; __hip_bfloat16* d; int n;
    switch (blockIdx.y) {
        case 0:  s = s0; d = d0; n = n0_; break;
        case 1:  s = s1; d = d1; n = n1_; break;
        case 2:  s = s2; d = d2; n = n2_; break;
        default: s = s3; d = d3; n = n3_; break;
    }
    const int idx = (blockIdx.x * 256 + threadIdx.x) * 8;
    if (idx < n) {
        float4 v0 = *(const float4*)(s + idx);
        float4 v1 = *(const float4*)(s + idx + 4);
        union { short8 sv; __hip_bfloat16 h[8]; } u;
        u.h[0] = __float2bfloat16(v0.x); u.h[1] = __float2bfloat16(v0.y);
        u.h[2] = __float2bfloat16(v0.z); u.h[3] = __float2bfloat16(v0.w);
        u.h[4] = __float2bfloat16(v1.x); u.h[5] = __float2bfloat16(v1.y);
        u.h[6] = __float2bfloat16(v1.z); u.h[7] = __float2bfloat16(v1.w);
        *(short8*)(d + idx) = u.sv;
    }
}

// ---------------------------------------------------------------------------
// Dual GEMM in one dispatch: blockIdx.z selects {A,W,bias,out,K}.
// 128x128 tile, BK=64, 4 waves (2x2), 4x4 mfma_f32_16x16x32_bf16 per wave.
// Staging: global_load_lds width=16, XOR-swizzled chunks.
// Epilogue: acc+bias -> padded LDS (stride 136) -> coalesced 16B stores.
// ~974 TF for the pair (R4 measured) — m97-structure plateau.
// ---------------------------------------------------------------------------
__global__ __launch_bounds__(256, 3)
void gemm_dual(const __hip_bfloat16* __restrict__ A0, const __hip_bfloat16* __restrict__ W0,
               const float* __restrict__ bias0, __hip_bfloat16* __restrict__ out0, int K0,
               const __hip_bfloat16* __restrict__ A1, const __hip_bfloat16* __restrict__ W1,
               const float* __restrict__ bias1, __hip_bfloat16* __restrict__ out1, int K1) {
    __shared__ alignas(16) __hip_bfloat16 smem[17408];
    __hip_bfloat16* sA = smem;
    __hip_bfloat16* sB = smem + 8192;

    const __hip_bfloat16* A;  const __hip_bfloat16* W;
    const float* bias;        __hip_bfloat16* out;  int K;
    if (blockIdx.z == 0) { A = A0; W = W0; bias = bias0; out = out0; K = K0; }
    else                 { A = A1; W = W1; bias = bias1; out = out1; K = K1; }

    const int t    = threadIdx.x;
    const int lane = t & 63;
    const int wave = t >> 6;
    const int quad = lane >> 4;
    const int rl   = lane & 15;
    const int wm   = (wave >> 1) * 64;
    const int wn   = (wave & 1) * 64;
    const int m0   = blockIdx.y * 128;
    const int n0   = blockIdx.x * 128;

    floatx4 acc[4][4];
    #pragma unroll
    for (int i = 0; i < 4; ++i)
        #pragma unroll
        for (int j = 0; j < 4; ++j)
            acc[i][j] = (floatx4){0.f, 0.f, 0.f, 0.f};

    int srow[4], scol[4];
    #pragma unroll
    for (int i = 0; i < 4; ++i) {
        const int cl  = (wave * 4 + i) * 64 + lane;
        const int row = cl >> 3;
        srow[i] = row;
        scol[i] = ((cl & 7) ^ (row & 7)) * 8;
    }

    for (int k0 = 0; k0 < K; k0 += 64) {
        __syncthreads();
        #pragma unroll
        for (int i = 0; i < 4; ++i) {
            load_lds16(A + (size_t)(m0 + srow[i]) * K + k0 + scol[i], sA + (wave * 4 + i) * 512);
            load_lds16(W + (size_t)(n0 + srow[i]) * K + k0 + scol[i], sB + (wave * 4 + i) * 512);
        }
        __syncthreads();
        #pragma unroll
        for (int kk = 0; kk < 2; ++kk) {
            short8 aF[4], bF[4];
            #pragma unroll
            for (int i = 0; i < 4; ++i) {
                const int r = wm + i * 16 + rl;
                const int c = kk * 4 + quad;
                aF[i] = *(const short8*)(sA + (r * 8 + (c ^ (r & 7))) * 8);
            }
            #pragma unroll
            for (int j = 0; j < 4; ++j) {
                const int r = wn + j * 16 + rl;
                const int c = kk * 4 + quad;
                bF[j] = *(const short8*)(sB + (r * 8 + (c ^ (r & 7))) * 8);
            }
            #pragma unroll
            for (int i = 0; i < 4; ++i)
                #pragma unroll
                for (int j = 0; j < 4; ++j)
                    acc[i][j] = __builtin_amdgcn_mfma_f32_16x16x32_bf16(aF[i], bF[j], acc[i][j], 0, 0, 0);
        }
    }

    __syncthreads();
    #pragma unroll
    for (int j = 0; j < 4; ++j) {
        const int col = wn + j * 16 + rl;
        const float bv = bias[n0 + col];
        #pragma unroll
        for (int i = 0; i < 4; ++i) {
            const int rbase = wm + i * 16 + quad * 4;
            #pragma unroll
            for (int r = 0; r < 4; ++r)
                smem[(rbase + r) * 136 + col] = __float2bfloat16(acc[i][j][r] + bv);
        }
    }
    __syncthreads();
    #pragma unroll
    for (int p = 0; p < 8; ++p) {
        const int ch  = p * 256 + t;
        const int row = ch >> 4;
        const int c8  = (ch & 15) * 8;
        short8 v = *(const short8*)(smem + row * 136 + c8);
        *(short8*)(out + (size_t)(m0 + row) * 4096 + n0 + c8) = v;
    }
}

// ---------------------------------------------------------------------------
// Single-pass LN+gates, 2 rows per block (128 threads/row), all 16B loads.
// Each wave lies entirely within one row: wave butterfly + 2-wave LDS combine.
// ---------------------------------------------------------------------------
__global__ __launch_bounds__(256)
void ln_gates(const __hip_bfloat16* __restrict__ Pi, const __hip_bfloat16* __restrict__ Ph,
              const float* __restrict__ c_prev,
              const float* __restrict__ g_in, const float* __restrict__ b_in,
              const float* __restrict__ g_hid, const float* __restrict__ b_hid,
              const float* __restrict__ g_cell, const float* __restrict__ b_cell,
              float* __restrict__ h_out, float* __restrict__ c_out) {
    const int t    = threadIdx.x;
    const int half = t >> 7;                 // row within block
    const int tt   = t & 127;
    const int wave = t >> 6;                 // 0..3 (waves 0,1 -> half 0; 2,3 -> half 1)
    const int row  = blockIdx.x * 2 + half;
    __shared__ float sred[4][6];

    const __hip_bfloat16* pi = Pi + (size_t)row * 4096;
    const __hip_bfloat16* ph = Ph + (size_t)row * 4096;
    const int j0 = tt * 8;

    // one 16B load per gate-region per matrix; values kept in registers
    float fpi[4][8], fph[4][8];
    float si = 0.f, sqi = 0.f, sh = 0.f, sqh = 0.f;
    #pragma unroll
    for (int g = 0; g < 4; ++g) {
        short8 vi = *(const short8*)(pi + g * 1024 + j0);
        short8 vh = *(const short8*)(ph + g * 1024 + j0);
        #pragma unroll
        for (int e = 0; e < 8; ++e) {
            const float a = b2f(vi[e]); fpi[g][e] = a; si += a; sqi += a * a;
            const float b = b2f(vh[e]); fph[g][e] = b; sh += b; sqh += b * b;
        }
    }
    floatx4 cp0 = *(const floatx4*)(c_prev + (size_t)row * 1024 + j0);
    floatx4 cp1 = *(const floatx4*)(c_prev + (size_t)row * 1024 + j0 + 4);

    // per-row stats: wave butterfly (64) then combine the row's two waves
    #pragma unroll
    for (int mask = 1; mask <= 32; mask <<= 1) {
        si += __shfl_xor(si, mask); sqi += __shfl_xor(sqi, mask);
        sh += __shfl_xor(sh, mask); sqh += __shfl_xor(sqh, mask);
    }
    if ((t & 63) == 0) {
        sred[wave][0] = si; sred[wave][1] = sqi;
        sred[wave][2] = sh; sred[wave][3] = sqh;
    }
    __syncthreads();
    const int wb = half * 2;
    si  = sred[wb][0] + sred[wb + 1][0];
    sqi = sred[wb][1] + sred[wb + 1][1];
    sh  = sred[wb][2] + sred[wb + 1][2];
    sqh = sred[wb][3] + sred[wb + 1][3];

    const float mu_i = si * (1.f / 4096.f);
    const float rs_i = rsqrtf(sqi * (1.f / 4096.f) - mu_i * mu_i + EPS);
    const float mu_h = sh * (1.f / 4096.f);
    const float rs_h = rsqrtf(sqh * (1.f / 4096.f) - mu_h * mu_h + EPS);

    float comb[4][8];
    #pragma unroll
    for (int g = 0; g < 4; ++g) {
        const int col = g * 1024 + j0;
        floatx4 gi0  = *(const floatx4*)(g_in  + col);
        floatx4 gi1  = *(const floatx4*)(g_in  + col + 4);
        floatx4 bi0  = *(const floatx4*)(b_in  + col);
        floatx4 bi1  = *(const floatx4*)(b_in  + col + 4);
        floatx4 gh0  = *(const floatx4*)(g_hid + col);
        floatx4 gh1  = *(const floatx4*)(g_hid + col + 4);
        floatx4 bh0  = *(const floatx4*)(b_hid + col);
        floatx4 bh1  = *(const floatx4*)(b_hid + col + 4);
        #pragma unroll
        for (int e = 0; e < 4; ++e) {
            comb[g][e]     = (fpi[g][e]     - mu_i) * rs_i * gi0[e] + bi0[e]
                           + (fph[g][e]     - mu_h) * rs_h * gh0[e] + bh0[e];
            comb[g][e + 4] = (fpi[g][e + 4] - mu_i) * rs_i * gi1[e] + bi1[e]
                           + (fph[g][e + 4] - mu_h) * rs_h * gh1[e] + bh1[e];
        }
    }

    float cn[8], ov[8];
    float sc = 0.f, scq = 0.f;
    #pragma unroll
    for (int e = 0; e < 8; ++e) {
        const float iv = sigmoidf_(comb[0][e]);
        const float fv = sigmoidf_(comb[1][e]);
        const float gv = tanhf_(comb[2][e]);
        ov[e] = sigmoidf_(comb[3][e]);
        const float cpv = (e < 4) ? cp0[e] : cp1[e - 4];
        const float c = fv * cpv + iv * gv;
        cn[e] = c; sc += c; scq += c * c;
    }
    #pragma unroll
    for (int mask = 1; mask <= 32; mask <<= 1) {
        sc += __shfl_xor(sc, mask); scq += __shfl_xor(scq, mask);
    }
    if ((t & 63) == 0) { sred[wave][4] = sc; sred[wave][5] = scq; }
    __syncthreads();
    sc  = sred[wb][4] + sred[wb + 1][4];
    scq = sred[wb][5] + sred[wb + 1][5];
    const float mu_c = sc * (1.f / 1024.f);
    const float rs_c = rsqrtf(scq * (1.f / 1024.f) - mu_c * mu_c + EPS);

    floatx4 gc0 = *(const floatx4*)(g_cell + j0);
    floatx4 gc1 = *(const floatx4*)(g_cell + j0 + 4);
    floatx4 bc0 = *(const floatx4*)(b_cell + j0);
    floatx4 bc1 = *(const floatx4*)(b_cell + j0 + 4);
    floatx4 hv0, hv1, cv0, cv1;
    #pragma unroll
    for (int e = 0; e < 4; ++e) {
        const float nc0 = (cn[e]     - mu_c) * rs_c * gc0[e] + bc0[e];
        const float nc1 = (cn[e + 4] - mu_c) * rs_c * gc1[e] + bc1[e];
        hv0[e] = ov[e] * tanhf_(nc0);
        hv1[e] = ov[e + 4] * tanhf_(nc1);
        cv0[e] = cn[e];
        cv1[e] = cn[e + 4];
    }
    float* hp = h_out + (size_t)row * 1024 + j0;
    float* cpout = c_out + (size_t)row * 1024 + j0;
    *(floatx4*)(hp) = hv0;     *(floatx4*)(hp + 4) = hv1;
    *(floatx4*)(cpout) = cv0;  *(floatx4*)(cpout + 4) = cv1;
}

// ---------------------------------------------------------------------------
extern "C" void kernel_launch(void* const* d_in, const int* in_sizes, int n_in,
                              void* d_out, int out_size, void* d_ws, size_t ws_size,
                              hipStream_t stream) {
    const float* x      = (const float*)d_in[0];
    const float* h_prev = (const float*)d_in[1];
    const float* c_prev = (const float*)d_in[2];
    const float* Wi     = (const float*)d_in[3];
    const float* bi     = (const float*)d_in[4];
    const float* Wh     = (const float*)d_in[5];
    const float* bh     = (const float*)d_in[6];
    const float* g_in   = (const float*)d_in[7];
    const float* b_in   = (const float*)d_in[8];
    const float* g_hid  = (const float*)d_in[9];
    const float* b_hid  = (const float*)d_in[10];
    const float* g_cell = (const float*)d_in[11];
    const float* b_cell = (const float*)d_in[12];

    __hip_bfloat16* Pi = (__hip_bfloat16*)d_ws;               // 64 MiB
    __hip_bfloat16* Ph = Pi + (size_t)8192 * 4096;            // 64 MiB

    // d_out doubles as scratch for bf16-converted inputs; ln_gates fully
    // overwrites all 64 MiB of d_out at the end of every call.
    const int NX = 8192 * 512, NH = 8192 * 1024, NWI = 4096 * 512, NWH = 4096 * 1024;
    __hip_bfloat16* xb  = (__hip_bfloat16*)d_out;
    __hip_bfloat16* hb  = xb + NX;
    __hip_bfloat16* Wib = hb + NH;
    __hip_bfloat16* Whb = Wib + NWI;

    float* h_out = (float*)d_out;
    float* c_out = h_out + (size_t)8192 * 1024;

    // max segment = 8M elems / 8 per thread / 256 per block = 4096 blocks
    hipLaunchKernelGGL(cvt_bf16, dim3(4096, 4), dim3(256), 0, stream,
                       x, xb, NX, h_prev, hb, NH, Wi, Wib, NWI, Wh, Whb, NWH);

    hipLaunchKernelGGL(gemm_dual, dim3(32, 64, 2), dim3(256), 0, stream,
                       xb, Wib, bi, Pi, 512,
                       hb, Whb, bh, Ph, 1024);

    hipLaunchKernelGGL(ln_gates, dim3(4096), dim3(256), 0, stream, Pi, Ph, c_prev,
                       g_in, b_in, g_hid, b_hid, g_cell, b_cell, h_out, c_out);
}